// Round 1
// baseline (357.565 us; speedup 1.0000x reference)
//
#include <hip/hip_runtime.h>

// DynamicMaskHead fused kernel (MI355X / gfx950)
// Per instance: rel-coords + gathered feats -> 10->8->8->1 MLP over 128x128,
// then aligned_bilinear x2 -> 256x256. Fused: logits tile in LDS, upsample
// straight to global. One block per (instance, half-image): grid = 2*n_inst.
//
// aligned_bilinear(factor=2) closed form (derived from pad/upsample/pad/slice):
//   out[Y][X] = bilerp over logits with
//     uy=max(Y-1,0), iy=uy>>1, fy=(uy&1)*0.5, iy1=min(iy+1,127)   (same for X)

#define HW   16384
#define IMGW 128
#define NP   169   // (8+2)*8 + 8*8 + 8 + 8 + 8 + 1

__global__ __launch_bounds__(256, 2)
void dmh_kernel(const float* __restrict__ mask_feats,   // (4,8,128,128)
                const float* __restrict__ mask_shift,   // (16384,2)
                const float* __restrict__ shifts,       // (n,2)
                const float* __restrict__ inst_params,  // (n,169)
                const int*   __restrict__ im_inds,      // (n,)
                const int*   __restrict__ fpn_levels,   // (n,)
                float*       __restrict__ out)          // (n,1,256,256)
{
    __shared__ float sp[NP];
    __shared__ float sc[3];
    __shared__ float tile[65 * IMGW];   // logits rows [rbase, rbase+65)

    const int inst  = blockIdx.x >> 1;
    const int half  = blockIdx.x & 1;
    const int tid   = threadIdx.x;
    const int rbase = 63 * half;        // half 0: rows 0..64, half 1: rows 63..127
    const int base  = rbase * IMGW;     // flat pixel offset of tile row 0

    if (tid < NP) sp[tid] = inst_params[inst * NP + tid];
    if (tid == 0) {
        sc[0] = shifts[2 * inst];
        sc[1] = shifts[2 * inst + 1];
        sc[2] = 1.0f / (float)(64 << fpn_levels[inst]);  // 1/SOI[level], exact pow2
    }
    __syncthreads();

    const float s0 = sc[0], s1 = sc[1], inv = sc[2];
    const float* featp = mask_feats + (size_t)im_inds[inst] * 8 * HW;

    // ---------------- phase 1: logits tile (65*128 = 8320 px) ----------------
    // main loop: 8 iters x 4 px/thread (covers 8192 px), then 128-px tail
    #pragma unroll 1
    for (int it = 0; it < 8; ++it) {
        const int t0 = it * 1024 + tid;

        float xx[4][10];
        #pragma unroll
        for (int j = 0; j < 4; ++j) {
            const int gp = base + t0 + j * 256;
            const float m0 = mask_shift[2 * gp];
            const float m1 = mask_shift[2 * gp + 1];
            xx[j][0] = (s0 - m0) * inv;
            xx[j][1] = (s1 - m1) * inv;
            #pragma unroll
            for (int c = 0; c < 8; ++c)
                xx[j][2 + c] = featp[c * HW + gp];
        }

        float y1[4][8];
        #pragma unroll
        for (int o = 0; o < 8; ++o) {
            const float bb = sp[152 + o];
            float a0 = bb, a1 = bb, a2 = bb, a3 = bb;
            #pragma unroll
            for (int c = 0; c < 10; ++c) {
                const float w = sp[o * 10 + c];
                a0 = fmaf(w, xx[0][c], a0);
                a1 = fmaf(w, xx[1][c], a1);
                a2 = fmaf(w, xx[2][c], a2);
                a3 = fmaf(w, xx[3][c], a3);
            }
            y1[0][o] = fmaxf(a0, 0.f); y1[1][o] = fmaxf(a1, 0.f);
            y1[2][o] = fmaxf(a2, 0.f); y1[3][o] = fmaxf(a3, 0.f);
        }

        float y2[4][8];
        #pragma unroll
        for (int o = 0; o < 8; ++o) {
            const float bb = sp[160 + o];
            float a0 = bb, a1 = bb, a2 = bb, a3 = bb;
            #pragma unroll
            for (int c = 0; c < 8; ++c) {
                const float w = sp[80 + o * 8 + c];
                a0 = fmaf(w, y1[0][c], a0);
                a1 = fmaf(w, y1[1][c], a1);
                a2 = fmaf(w, y1[2][c], a2);
                a3 = fmaf(w, y1[3][c], a3);
            }
            y2[0][o] = fmaxf(a0, 0.f); y2[1][o] = fmaxf(a1, 0.f);
            y2[2][o] = fmaxf(a2, 0.f); y2[3][o] = fmaxf(a3, 0.f);
        }

        float l0 = sp[168], l1 = l0, l2 = l0, l3 = l0;
        #pragma unroll
        for (int c = 0; c < 8; ++c) {
            const float w = sp[144 + c];
            l0 = fmaf(w, y2[0][c], l0);
            l1 = fmaf(w, y2[1][c], l1);
            l2 = fmaf(w, y2[2][c], l2);
            l3 = fmaf(w, y2[3][c], l3);
        }
        tile[t0]       = l0;
        tile[t0 + 256] = l1;
        tile[t0 + 512] = l2;
        tile[t0 + 768] = l3;
    }

    // tail: pixels 8192..8319
    if (tid < 128) {
        const int t  = 8192 + tid;
        const int gp = base + t;
        float xx[10];
        xx[0] = (s0 - mask_shift[2 * gp]) * inv;
        xx[1] = (s1 - mask_shift[2 * gp + 1]) * inv;
        #pragma unroll
        for (int c = 0; c < 8; ++c) xx[2 + c] = featp[c * HW + gp];

        float y1[8];
        #pragma unroll
        for (int o = 0; o < 8; ++o) {
            float a = sp[152 + o];
            #pragma unroll
            for (int c = 0; c < 10; ++c) a = fmaf(sp[o * 10 + c], xx[c], a);
            y1[o] = fmaxf(a, 0.f);
        }
        float y2[8];
        #pragma unroll
        for (int o = 0; o < 8; ++o) {
            float a = sp[160 + o];
            #pragma unroll
            for (int c = 0; c < 8; ++c) a = fmaf(sp[80 + o * 8 + c], y1[c], a);
            y2[o] = fmaxf(a, 0.f);
        }
        float lg = sp[168];
        #pragma unroll
        for (int c = 0; c < 8; ++c) lg = fmaf(sp[144 + c], y2[c], lg);
        tile[t] = lg;
    }

    __syncthreads();

    // ---------------- phase 2: upsample 128 rows x 256 cols ----------------
    float* outp = out + (size_t)inst * 65536;
    #pragma unroll 1
    for (int it = 0; it < 32; ++it) {
        const int idx = it * 256 + tid;
        const int y   = idx >> 6;        // 64 float4 per output row
        const int l   = idx & 63;
        const int Y   = 128 * half + y;

        const int   uy = (Y > 0) ? (Y - 1) : 0;
        const int   iy = uy >> 1;
        const float fy = (uy & 1) ? 0.5f : 0.f;
        const int   iy1 = min(iy + 1, 127);
        const float* r0 = &tile[(iy  - rbase) * IMGW];
        const float* r1 = &tile[(iy1 - rbase) * IMGW];

        float res[4];
        #pragma unroll
        for (int j = 0; j < 4; ++j) {
            const int   X  = 4 * l + j;
            const int   ux = (X > 0) ? (X - 1) : 0;
            const int   ix = ux >> 1;
            const float fx = (ux & 1) ? 0.5f : 0.f;
            const int   ix1 = min(ix + 1, 127);
            const float a = r0[ix] * (1.f - fx) + r0[ix1] * fx;
            const float c = r1[ix] * (1.f - fx) + r1[ix1] * fx;
            res[j] = a * (1.f - fy) + c * fy;
        }
        *(float4*)(outp + Y * 256 + 4 * l) =
            make_float4(res[0], res[1], res[2], res[3]);
    }
}

extern "C" void kernel_launch(void* const* d_in, const int* in_sizes, int n_in,
                              void* d_out, int out_size, void* d_ws, size_t ws_size,
                              hipStream_t stream) {
    (void)n_in; (void)out_size; (void)d_ws; (void)ws_size;
    const float* mask_feats  = (const float*)d_in[0];
    const float* mask_shift  = (const float*)d_in[1];
    const float* shifts      = (const float*)d_in[2];
    const float* inst_params = (const float*)d_in[3];
    const int*   im_inds     = (const int*)d_in[4];
    const int*   fpn_levels  = (const int*)d_in[5];
    // d_in[6] = mask_feat_stride (==8 in this problem; factor 2 hardcoded)
    float* out = (float*)d_out;

    const int n_inst = in_sizes[2] / 2;   // shifts is (n,2)
    dmh_kernel<<<dim3(2 * n_inst), dim3(256), 0, stream>>>(
        mask_feats, mask_shift, shifts, inst_params, im_inds, fpn_levels, out);
}

// Round 2
// 210.499 us; speedup vs baseline: 1.6987x; 1.6987x over previous
//
#include <hip/hip_runtime.h>

// DynamicMaskHead fused, reuse-inverted (MI355X / gfx950)
// grid = 4 images x 16 row-groups x 16 instance-chunks = 1024 blocks.
// Block preloads feats/shift for logits rows [r0-1, r0+8) into REGISTERS,
// then loops over its chunk's instances with im_inds==img:
//   MLP (10->8->8->1, weights via uniform scalar loads) -> logits in LDS
//   -> x2 aligned_bilinear upsample -> float4 stores of output rows
//   [2*r0, 2*r0+16).
//
// aligned_bilinear(factor=2) closed form:
//   uy=max(Y-1,0), iy=uy>>1, fy=(uy&1)*0.5, iy1=min(iy+1,127); same for X.
// Output rows [2r0,2r0+16) need logits rows [r0-1, r0+7] -> 9-row tile,
// halo ABOVE (row r0-1), none below (fy=0 exactly when iy1 would exceed).

#define HW 16384
#define NP 169
#define NCHUNK 16

__global__ __launch_bounds__(256, 4)
void dmh_kernel(const float* __restrict__ mask_feats,   // (4,8,128,128)
                const float* __restrict__ mask_shift,   // (16384,2)
                const float* __restrict__ shifts,       // (n,2)
                const float* __restrict__ inst_params,  // (n,169)
                const int*   __restrict__ im_inds,      // (n,)
                const int*   __restrict__ fpn_levels,   // (n,)
                float*       __restrict__ out,          // (n,1,256,256)
                int n_inst, int chunk)
{
    __shared__ float lg[1152];          // logits tile: 9 rows x 128 cols

    const int bx  = blockIdx.x;
    const int img = bx & 3;
    const int rg  = (bx >> 2) & 15;
    const int ck  = bx >> 6;
    const int tid = threadIdx.x;
    const int r0  = rg * 8;

    // ---- preload this thread's pixels (px p = tid + 256k, k=0..4) ----
    // tile row t = p>>7 maps to logits row r0-1+t (clamped; row -1 unread)
    float f[5][8], m0[5], m1[5];
    const float* fb = mask_feats + (size_t)img * 8 * HW;
    #pragma unroll
    for (int k = 0; k < 5; ++k) {
        int p = tid + 256 * k;
        int r = r0 - 1 + (p >> 7);
        r = max(r, 0); r = min(r, 127);     // clamp keeps loads in-bounds
        int g = r * 128 + (p & 127);
        m0[k] = mask_shift[2 * g];
        m1[k] = mask_shift[2 * g + 1];
        #pragma unroll
        for (int c = 0; c < 8; ++c) f[k][c] = fb[c * HW + g];
    }

    const int i0 = ck * chunk;
    const int i1 = min(i0 + chunk, n_inst);

    for (int i = i0; i < i1; ++i) {
        if (im_inds[i] != img) continue;        // block-uniform branch

        const float* __restrict__ wp = inst_params + (size_t)i * NP;
        const float s0  = shifts[2 * i];
        const float s1  = shifts[2 * i + 1];
        const float inv = 1.0f / (float)(64 << fpn_levels[i]);

        // ---- phase A: per-pixel MLP -> logits LDS ----
        auto mlp_px = [&](int k) {
            const float x0 = (s0 - m0[k]) * inv;
            const float x1 = (s1 - m1[k]) * inv;
            float y1[8];
            #pragma unroll
            for (int o = 0; o < 8; ++o) {
                float a = wp[152 + o];
                a = fmaf(wp[o * 10], x0, a);
                a = fmaf(wp[o * 10 + 1], x1, a);
                #pragma unroll
                for (int c = 0; c < 8; ++c)
                    a = fmaf(wp[o * 10 + 2 + c], f[k][c], a);
                y1[o] = fmaxf(a, 0.f);
            }
            float y2[8];
            #pragma unroll
            for (int o = 0; o < 8; ++o) {
                float a = wp[160 + o];
                #pragma unroll
                for (int c = 0; c < 8; ++c)
                    a = fmaf(wp[80 + o * 8 + c], y1[c], a);
                y2[o] = fmaxf(a, 0.f);
            }
            float v = wp[168];
            #pragma unroll
            for (int c = 0; c < 8; ++c)
                v = fmaf(wp[144 + c], y2[c], v);
            lg[tid + 256 * k] = v;
        };
        #pragma unroll
        for (int k = 0; k < 4; ++k) mlp_px(k);
        if (tid < 128) mlp_px(4);               // wave-uniform (waves 2,3 skip)

        __syncthreads();

        // ---- phase B: upsample 16 output rows x 256 cols, float4 stores ----
        float* op = out + (size_t)i * 65536 + (size_t)(2 * r0) * 256;
        #pragma unroll
        for (int j = 0; j < 4; ++j) {
            const int q  = tid + 256 * j;
            const int yl = q >> 6;              // wave-uniform output row
            const int l  = q & 63;
            const int Y  = 2 * r0 + yl;
            const int uy = max(Y - 1, 0);
            const int t0 = (uy >> 1) - (r0 - 1);
            const float fy = (uy & 1) ? 0.5f : 0.f;
            const int t1 = min(t0 + 1, 8);      // fy==0 exactly when clamped
            const float* ra = &lg[t0 * 128];
            const float* rb = &lg[t1 * 128];
            float res[4];
            #pragma unroll
            for (int jj = 0; jj < 4; ++jj) {
                const int X  = 4 * l + jj;
                const int ux = max(X - 1, 0);
                const int ix = ux >> 1;
                const float fx = (ux & 1) ? 0.5f : 0.f;
                const int ix1 = min(ix + 1, 127);
                const float a = ra[ix] * (1.f - fx) + ra[ix1] * fx;
                const float b = rb[ix] * (1.f - fx) + rb[ix1] * fx;
                res[jj] = a * (1.f - fy) + b * fy;
            }
            *(float4*)(op + yl * 256 + 4 * l) =
                make_float4(res[0], res[1], res[2], res[3]);
        }
        __syncthreads();                        // lg reused next instance
    }
}

extern "C" void kernel_launch(void* const* d_in, const int* in_sizes, int n_in,
                              void* d_out, int out_size, void* d_ws, size_t ws_size,
                              hipStream_t stream) {
    (void)n_in; (void)out_size; (void)d_ws; (void)ws_size;
    const float* mask_feats  = (const float*)d_in[0];
    const float* mask_shift  = (const float*)d_in[1];
    const float* shifts      = (const float*)d_in[2];
    const float* inst_params = (const float*)d_in[3];
    const int*   im_inds     = (const int*)d_in[4];
    const int*   fpn_levels  = (const int*)d_in[5];
    float* out = (float*)d_out;

    const int n_inst = in_sizes[2] / 2;             // shifts is (n,2)
    const int chunk  = (n_inst + NCHUNK - 1) / NCHUNK;
    dmh_kernel<<<dim3(4 * 16 * NCHUNK), dim3(256), 0, stream>>>(
        mask_feats, mask_shift, shifts, inst_params, im_inds, fpn_levels, out,
        n_inst, chunk);
}

// Round 3
// 167.394 us; speedup vs baseline: 2.1361x; 1.2575x over previous
//
#include <hip/hip_runtime.h>

// DynamicMaskHead fused v3 (MI355X / gfx950)
// grid = n_inst x 16 row-groups = 6400 equal blocks, 256 threads.
// Block (inst, rg): computes logits rows [r0-1, r0+8) (9x128, halo above)
// via the 10->8->8->1 MLP with block-uniform scalar weight loads, stores
// them even/odd-column-split in LDS, then emits output rows [2r0, 2r0+16)
// (16x256) with factor-2 aligned_bilinear closed form and float4 stores.
//
// aligned_bilinear(factor=2):
//   uy=max(Y-1,0): odd Y -> fy=0 (copy logits row (Y-1)/2);
//   even Y -> fy=0.5 (avg rows Y/2-1, Y/2); Y=0 -> row 0 (halo row of rg=0
//   is a bitwise duplicate of row 0 via clamped loads, so no special case).
//   Same structure in X: out[4l..4l+3] from logits cols {2l-1, 2l, 2l+1}.

#define HW 16384
#define NP 169

__global__ __launch_bounds__(256, 8)
void dmh_kernel(const float* __restrict__ mask_feats,   // (4,8,128,128)
                const float* __restrict__ mask_shift,   // (16384,2)
                const float* __restrict__ shifts,       // (n,2)
                const float* __restrict__ inst_params,  // (n,169)
                const int*   __restrict__ im_inds,      // (n,)
                const int*   __restrict__ fpn_levels,   // (n,)
                float*       __restrict__ out)          // (n,1,256,256)
{
    __shared__ float lgE[576];   // 9 rows x 64 even cols
    __shared__ float lgO[576];   // 9 rows x 64 odd  cols

    const int bx   = blockIdx.x;
    const int inst = bx >> 4;
    const int rg   = bx & 15;
    const int tid  = threadIdx.x;
    const int r0   = rg * 8;

    const float* __restrict__ fb =
        mask_feats + (size_t)im_inds[inst] * 8 * HW;
    const float* __restrict__ wp = inst_params + (size_t)inst * NP;
    const float s0  = shifts[2 * inst];
    const float s1  = shifts[2 * inst + 1];
    const float inv = 1.0f / (float)(64 << fpn_levels[inst]);

    // ---- phase A: MLP over 9x128 logits tile (4.5 px/thread) ----
    auto mlp_px = [&](int p) {
        const int t = p >> 7;            // tile row 0..8
        const int c = p & 127;
        const int r = min(max(r0 - 1 + t, 0), 127);
        const int g = r * 128 + c;

        const float2 ms = *(const float2*)(mask_shift + 2 * g);
        const float x0 = (s0 - ms.x) * inv;
        const float x1 = (s1 - ms.y) * inv;
        float f[8];
        #pragma unroll
        for (int k = 0; k < 8; ++k) f[k] = fb[k * HW + g];

        float y1[8];
        #pragma unroll
        for (int o = 0; o < 8; ++o) {
            float a = wp[152 + o];
            a = fmaf(wp[o * 10], x0, a);
            a = fmaf(wp[o * 10 + 1], x1, a);
            #pragma unroll
            for (int k = 0; k < 8; ++k) a = fmaf(wp[o * 10 + 2 + k], f[k], a);
            y1[o] = fmaxf(a, 0.f);
        }
        float y2[8];
        #pragma unroll
        for (int o = 0; o < 8; ++o) {
            float a = wp[160 + o];
            #pragma unroll
            for (int k = 0; k < 8; ++k) a = fmaf(wp[80 + o * 8 + k], y1[k], a);
            y2[o] = fmaxf(a, 0.f);
        }
        float v = wp[168];
        #pragma unroll
        for (int k = 0; k < 8; ++k) v = fmaf(wp[144 + k], y2[k], v);

        const int idx = t * 64 + (c >> 1);
        if (c & 1) lgO[idx] = v; else lgE[idx] = v;
    };

    mlp_px(tid);
    mlp_px(tid + 256);
    mlp_px(tid + 512);
    mlp_px(tid + 768);
    if (tid < 128) mlp_px(tid + 1024);   // waves 0,1 only (wave-uniform)

    __syncthreads();

    // ---- phase B: upsample 16 rows x 256 cols, float4 stores ----
    float* __restrict__ op =
        out + (size_t)inst * 65536 + (size_t)(2 * r0) * 256;
    const int w = tid >> 6;              // wave id -> row parity uniform
    const int l = tid & 63;

    #pragma unroll
    for (int j = 0; j < 4; ++j) {
        const int yl = w + 4 * j;
        float4 res;
        if (w & 1) {                     // odd output row: fy = 0
            const int t0 = (yl + 1) >> 1;
            const float* e = lgE + t0 * 64;
            const float* o = lgO + t0 * 64;
            const float v0 = e[l];
            const float v1 = o[l];
            const float vm = (l > 0) ? o[l - 1] : v0;
            res = make_float4(0.5f * (vm + v0), v0, 0.5f * (v0 + v1), v1);
        } else {                         // even output row: fy = 0.5
            const int t0 = yl >> 1;
            const float* eA = lgE + t0 * 64;
            const float* oA = lgO + t0 * 64;
            const float* eB = eA + 64;
            const float* oB = oA + 64;
            const float v0A = eA[l], v1A = oA[l];
            const float v0B = eB[l], v1B = oB[l];
            const float vmA = (l > 0) ? oA[l - 1] : v0A;
            const float vmB = (l > 0) ? oB[l - 1] : v0B;
            const float hA0 = 0.5f * (vmA + v0A), hA2 = 0.5f * (v0A + v1A);
            const float hB0 = 0.5f * (vmB + v0B), hB2 = 0.5f * (v0B + v1B);
            res = make_float4(0.5f * (hA0 + hB0), 0.5f * (v0A + v0B),
                              0.5f * (hA2 + hB2), 0.5f * (v1A + v1B));
        }
        *(float4*)(op + yl * 256 + 4 * l) = res;
    }
}

extern "C" void kernel_launch(void* const* d_in, const int* in_sizes, int n_in,
                              void* d_out, int out_size, void* d_ws, size_t ws_size,
                              hipStream_t stream) {
    (void)n_in; (void)out_size; (void)d_ws; (void)ws_size;
    const float* mask_feats  = (const float*)d_in[0];
    const float* mask_shift  = (const float*)d_in[1];
    const float* shifts      = (const float*)d_in[2];
    const float* inst_params = (const float*)d_in[3];
    const int*   im_inds     = (const int*)d_in[4];
    const int*   fpn_levels  = (const int*)d_in[5];
    float* out = (float*)d_out;

    const int n_inst = in_sizes[2] / 2;   // shifts is (n,2)
    dmh_kernel<<<dim3(n_inst * 16), dim3(256), 0, stream>>>(
        mask_feats, mask_shift, shifts, inst_params, im_inds, fpn_levels, out);
}

// Round 4
// 152.581 us; speedup vs baseline: 2.3434x; 1.0971x over previous
//
#include <hip/hip_runtime.h>

// DynamicMaskHead fused v4 (MI355X / gfx950)
// pack_kernel: mask_feats (4,8,128,128) -> rec (4,16384,8) pixel-major in ws.
// dmh_kernel: grid = n_inst x 8 row-groups (16 logits rows -> 32 out rows).
//   Block: 17x128 logits tile (halo row above, clamped) via 10->8->8->1 MLP
//   (block-uniform scalar weights, pixel feats via 2x dwordx4), parity-split
//   LDS, factor-2 aligned_bilinear closed form, float4 stores.
//
// aligned_bilinear(factor=2): uy=max(Y-1,0); odd Y -> copy logits row
// (Y-1)/2; even Y -> avg rows (Y/2-1, Y/2); Y=0 falls out via clamped halo.
// Same in X: out[4l..4l+3] from logits cols {2l-1, 2l, 2l+1}.

#define HW 16384
#define NP 169

__global__ __launch_bounds__(256)
void pack_kernel(const float* __restrict__ mf, float* __restrict__ rec)
{
    const int g   = blockIdx.x * 256 + threadIdx.x;   // 0..65535
    const int img = g >> 14;
    const int p   = g & 16383;
    const float* fb = mf + (size_t)img * 8 * HW + p;
    float4 a = make_float4(fb[0],      fb[HW],     fb[2 * HW], fb[3 * HW]);
    float4 b = make_float4(fb[4 * HW], fb[5 * HW], fb[6 * HW], fb[7 * HW]);
    float4* o = (float4*)(rec + (size_t)g * 8);
    o[0] = a;
    o[1] = b;
}

__global__ __launch_bounds__(256, 6)
void dmh_kernel(const float* __restrict__ mask_feats,   // (4,8,128,128)
                const float* __restrict__ mask_shift,   // (16384,2)
                const float* __restrict__ shifts,       // (n,2)
                const float* __restrict__ inst_params,  // (n,169)
                const int*   __restrict__ im_inds,      // (n,)
                const int*   __restrict__ fpn_levels,   // (n,)
                const float* __restrict__ rec,          // (4,16384,8) or null
                float*       __restrict__ out,          // (n,1,256,256)
                int use_rec)
{
    __shared__ float lgE[17 * 64];   // even cols
    __shared__ float lgO[17 * 64];   // odd cols

    const int bx   = blockIdx.x;
    const int inst = bx >> 3;
    const int rg   = bx & 7;
    const int tid  = threadIdx.x;
    const int r0   = rg * 16;

    const int img = im_inds[inst];
    const float* __restrict__ wp = inst_params + (size_t)inst * NP;
    const float s0  = shifts[2 * inst];
    const float s1  = shifts[2 * inst + 1];
    const float inv = 1.0f / (float)(64 << fpn_levels[inst]);
    const float* __restrict__ fb = mask_feats + (size_t)img * 8 * HW;
    const float* __restrict__ rb = rec + (size_t)img * 8 * HW;

    // ---- phase A: MLP over 17x128 tile (pixel p -> tile row p>>7) ----
    auto load_px = [&](int p, float* x) {
        const int t = p >> 7;
        const int c = p & 127;
        const int r = min(max(r0 - 1 + t, 0), 127);
        const int g = r * 128 + c;
        const float2 ms = *(const float2*)(mask_shift + 2 * g);
        x[0] = (s0 - ms.x) * inv;
        x[1] = (s1 - ms.y) * inv;
        if (use_rec) {
            const float4* q = (const float4*)(rb + (size_t)g * 8);
            const float4 a = q[0], b = q[1];
            x[2] = a.x; x[3] = a.y; x[4] = a.z; x[5] = a.w;
            x[6] = b.x; x[7] = b.y; x[8] = b.z; x[9] = b.w;
        } else {
            #pragma unroll
            for (int k = 0; k < 8; ++k) x[2 + k] = fb[k * HW + g];
        }
    };

    auto store_px = [&](int p, float v) {
        const int t = p >> 7;
        const int c = p & 127;
        const int idx = t * 64 + (c >> 1);
        if (c & 1) lgO[idx] = v; else lgE[idx] = v;
    };

    // pair-processing: 4 pair-calls cover 2048 px, tail covers 128
    #pragma unroll
    for (int u = 0; u < 4; ++u) {
        const int pA = tid + 512 * u;
        const int pB = pA + 256;
        float xa[10], xb[10];
        load_px(pA, xa);
        load_px(pB, xb);

        float ya[8], yb[8];
        #pragma unroll
        for (int o = 0; o < 8; ++o) {
            const float bia = wp[152 + o];
            float a = bia, b = bia;
            #pragma unroll
            for (int c = 0; c < 10; ++c) {
                const float w = wp[o * 10 + c];
                a = fmaf(w, xa[c], a);
                b = fmaf(w, xb[c], b);
            }
            ya[o] = fmaxf(a, 0.f);
            yb[o] = fmaxf(b, 0.f);
        }
        float za[8], zb[8];
        #pragma unroll
        for (int o = 0; o < 8; ++o) {
            const float bia = wp[160 + o];
            float a = bia, b = bia;
            #pragma unroll
            for (int c = 0; c < 8; ++c) {
                const float w = wp[80 + o * 8 + c];
                a = fmaf(w, ya[c], a);
                b = fmaf(w, yb[c], b);
            }
            za[o] = fmaxf(a, 0.f);
            zb[o] = fmaxf(b, 0.f);
        }
        float va = wp[168], vb = va;
        #pragma unroll
        for (int c = 0; c < 8; ++c) {
            const float w = wp[144 + c];
            va = fmaf(w, za[c], va);
            vb = fmaf(w, zb[c], vb);
        }
        store_px(pA, va);
        store_px(pB, vb);
    }

    if (tid < 128) {                 // tail px 2048..2175, waves 0-1 only
        const int p = 2048 + tid;
        float x[10];
        load_px(p, x);
        float y1[8];
        #pragma unroll
        for (int o = 0; o < 8; ++o) {
            float a = wp[152 + o];
            #pragma unroll
            for (int c = 0; c < 10; ++c) a = fmaf(wp[o * 10 + c], x[c], a);
            y1[o] = fmaxf(a, 0.f);
        }
        float y2[8];
        #pragma unroll
        for (int o = 0; o < 8; ++o) {
            float a = wp[160 + o];
            #pragma unroll
            for (int c = 0; c < 8; ++c) a = fmaf(wp[80 + o * 8 + c], y1[c], a);
            y2[o] = fmaxf(a, 0.f);
        }
        float v = wp[168];
        #pragma unroll
        for (int c = 0; c < 8; ++c) v = fmaf(wp[144 + c], y2[c], v);
        store_px(p, v);
    }

    __syncthreads();

    // ---- phase B: 32 output rows x 256 cols, float4 stores ----
    float* __restrict__ op =
        out + (size_t)inst * 65536 + (size_t)(2 * r0) * 256;
    const int w = tid >> 6;
    const int l = tid & 63;
    const int parity = w & 1;        // wave-uniform row parity

    #pragma unroll
    for (int j = 0; j < 8; ++j) {
        const int p2 = (w >> 1) + 2 * j;     // 0..15
        const int yl = 2 * p2 + parity;
        float4 res;
        if (parity) {                // odd row: fy=0, logits row p2+1
            const float* e = lgE + (p2 + 1) * 64;
            const float* o = lgO + (p2 + 1) * 64;
            const float v0 = e[l];
            const float v1 = o[l];
            const float vm = (l > 0) ? o[l - 1] : v0;
            res = make_float4(0.5f * (vm + v0), v0, 0.5f * (v0 + v1), v1);
        } else {                     // even row: fy=0.5, rows p2, p2+1
            const float* eA = lgE + p2 * 64;
            const float* oA = lgO + p2 * 64;
            const float* eB = eA + 64;
            const float* oB = oA + 64;
            const float v0A = eA[l], v1A = oA[l];
            const float v0B = eB[l], v1B = oB[l];
            const float vmA = (l > 0) ? oA[l - 1] : v0A;
            const float vmB = (l > 0) ? oB[l - 1] : v0B;
            res = make_float4(0.25f * (vmA + v0A + vmB + v0B),
                              0.5f  * (v0A + v0B),
                              0.25f * (v0A + v1A + v0B + v1B),
                              0.5f  * (v1A + v1B));
        }
        *(float4*)(op + yl * 256 + 4 * l) = res;
    }
}

extern "C" void kernel_launch(void* const* d_in, const int* in_sizes, int n_in,
                              void* d_out, int out_size, void* d_ws, size_t ws_size,
                              hipStream_t stream) {
    (void)n_in; (void)out_size;
    const float* mask_feats  = (const float*)d_in[0];
    const float* mask_shift  = (const float*)d_in[1];
    const float* shifts      = (const float*)d_in[2];
    const float* inst_params = (const float*)d_in[3];
    const int*   im_inds     = (const int*)d_in[4];
    const int*   fpn_levels  = (const int*)d_in[5];
    float* out = (float*)d_out;
    float* rec = (float*)d_ws;

    const int n_inst = in_sizes[2] / 2;            // shifts is (n,2)
    const size_t rec_bytes = (size_t)4 * HW * 8 * sizeof(float);
    const int use_rec = (ws_size >= rec_bytes) ? 1 : 0;

    if (use_rec)
        pack_kernel<<<dim3(4 * HW / 256), dim3(256), 0, stream>>>(
            mask_feats, rec);

    dmh_kernel<<<dim3(n_inst * 8), dim3(256), 0, stream>>>(
        mask_feats, mask_shift, shifts, inst_params, im_inds, fpn_levels,
        rec, out, use_rec);
}